// Round 5
// baseline (333.660 us; speedup 1.0000x reference)
//
#include <hip/hip_runtime.h>

typedef _Float16 f16;
typedef _Float16 half8 __attribute__((ext_vector_type(8)));
typedef _Float16 half4 __attribute__((ext_vector_type(4)));
typedef float f32x4 __attribute__((ext_vector_type(4)));

#define B_SZ 512
#define NQ   128
#define CH   512
#define NH   8
#define DH   64
#define MTOK (B_SZ*NQ)   // 65536 tokens
#define KD   512

#define MFMA16(a,b,c) __builtin_amdgcn_mfma_f32_16x16x32_f16((a),(b),(c),0,0,0)

// global -> LDS direct DMA, 16B per lane. LDS dest is wave-uniform base + lane*16.
#define GLDS16(g,l) __builtin_amdgcn_global_load_lds( \
    (__attribute__((address_space(1))) void*)(g), \
    (__attribute__((address_space(3))) void*)(l), 16, 0, 0)

// ---------------- kernel 0: x fp32->fp16  +  W^T fp32->fp16, one launch ----------------
// blocks 0..511: wt rows (4 each). blocks 512..2559: grid-stride cvt of x.
__global__ __launch_bounds__(256) void k_prep(
    const float* __restrict__ x,
    const float* __restrict__ Wq, const float* __restrict__ Wk,
    const float* __restrict__ Wv, const float* __restrict__ Wo,
    f16* __restrict__ xb, f16* __restrict__ wt) {
  const int bid = blockIdx.x;
  if (bid < 512) {
    for (int e = threadIdx.x; e < 2048; e += 256) {
      const int n = bid * 4 + (e >> 9);
      const int k = e & 511;
      const float* W = (n < 512) ? Wq : (n < 1024) ? Wk : (n < 1536) ? Wv : Wo;
      wt[n * 512 + k] = (f16)W[k * 512 + (n & 511)];
    }
  } else {
    const int n8 = MTOK * KD / 8;
    int i = (bid - 512) * 256 + threadIdx.x;
    const int stride = 2048 * 256;
    for (; i < n8; i += stride) {
      f32x4 a = ((const f32x4*)x)[2 * i];
      f32x4 b = ((const f32x4*)x)[2 * i + 1];
      half8 h;
      h[0] = (f16)a[0]; h[1] = (f16)a[1]; h[2] = (f16)a[2]; h[3] = (f16)a[3];
      h[4] = (f16)b[0]; h[5] = (f16)b[1]; h[6] = (f16)b[2]; h[7] = (f16)b[3];
      ((half8*)xb)[i] = h;
    }
  }
}

// ========== 128x128 GEMM core, BK=32, triple-buffered 2-tile-deep prefetch ==========
// LDS tiles swizzled (T2): LDS[row][slot] holds global slot (slot ^ ((row>>1)&3)),
// slot = 8-f16 chunk; applied as pre-swizzled global SOURCE (linear GLDS dest) +
// swizzled ds_read (lane-constant XOR). Counted vmcnt(4) gates: 4 GLDS/step, the
// newest 4 outstanding at each gate are tile t+2's -> tile t+1 landed. Never drains
// to 0 mid-loop (T4). K = 512 -> 16 tiles; bufs rotate mod 3 via pointer swap.
__device__ __forceinline__ void step128(const f16* pa, const f16* pb,
                                        int roA, int roB, f32x4 (&acc)[4][4]) {
  half8 af[4], bf[4];
#pragma unroll
  for (int m = 0; m < 4; ++m) af[m] = *(const half8*)(pa + roA + m * 512);
#pragma unroll
  for (int n = 0; n < 4; ++n) bf[n] = *(const half8*)(pb + roB + n * 512);
  __builtin_amdgcn_s_setprio(1);
#pragma unroll
  for (int m = 0; m < 4; ++m)
#pragma unroll
    for (int n = 0; n < 4; ++n)
      acc[m][n] = MFMA16(af[m], bf[n], acc[m][n]);
  __builtin_amdgcn_s_setprio(0);
}

__device__ __forceinline__ void gemm128_pf(
    const f16* __restrict__ Ag, const f16* __restrict__ Bg,  // pre-offset to tile row 0
    f16* la, f16* lb, f32x4 (&acc)[4][4]) {
  const int tid = threadIdx.x;
  const int w = tid >> 6, lane = tid & 63;
  const int ln = lane & 15, g = lane >> 4;
  const int wr = w >> 1, wc = w & 1;
  const int srow = w * 16 + (lane >> 2);
  const int scol = ((lane & 3) ^ ((lane >> 3) & 3)) * 8;   // pre-swizzled source slot
  const f16* gA = Ag + srow * KD + scol;
  const f16* gB = Bg + srow * KD + scol;
  const int w512 = w * 512;
  f16 *pa0 = la, *pa1 = la + 4096, *pa2 = la + 8192;
  f16 *pb0 = lb, *pb1 = lb + 4096, *pb2 = lb + 8192;
  const int slotx = (g ^ ((ln >> 1) & 3)) * 8;             // swizzled read slot
  const int roA = (wr * 64 + ln) * 32 + slotx;
  const int roB = (wc * 64 + ln) * 32 + slotx;

  // prologue: tiles 0 and 1 in flight; wait only tile 0 (vmcnt(4))
  GLDS16(gA,           pa0 + w512); GLDS16(gA + 64*KD,      pa0 + w512 + 2048);
  GLDS16(gB,           pb0 + w512); GLDS16(gB + 64*KD,      pb0 + w512 + 2048);
  GLDS16(gA + 32,      pa1 + w512); GLDS16(gA + 64*KD + 32, pa1 + w512 + 2048);
  GLDS16(gB + 32,      pb1 + w512); GLDS16(gB + 64*KD + 32, pb1 + w512 + 2048);
  asm volatile("s_waitcnt vmcnt(4)" ::: "memory");
  __builtin_amdgcn_s_barrier();

  const f16* gAs = gA + 64;   // tile 2 onward
  const f16* gBs = gB + 64;
#pragma unroll 1
  for (int t = 0; t < 14; ++t) {
    GLDS16(gAs, pa2 + w512); GLDS16(gAs + 64*KD, pa2 + w512 + 2048);
    GLDS16(gBs, pb2 + w512); GLDS16(gBs + 64*KD, pb2 + w512 + 2048);
    gAs += 32; gBs += 32;
    step128(pa0, pb0, roA, roB, acc);
    asm volatile("s_waitcnt vmcnt(4)" ::: "memory");   // tile t+1 landed
    __builtin_amdgcn_s_barrier();
    f16* t1 = pa0; pa0 = pa1; pa1 = pa2; pa2 = t1;
    f16* t2 = pb0; pb0 = pb1; pb1 = pb2; pb2 = t2;
  }
  // tile 14 (no staging left), then drain for tile 15
  step128(pa0, pb0, roA, roB, acc);
  asm volatile("s_waitcnt vmcnt(0)" ::: "memory");
  __builtin_amdgcn_s_barrier();
  step128(pa1, pb1, roA, roB, acc);
}

// ---------------- kernel 1: fused QKV projection GEMM ----------------
// XCD mapping: xcd = bid&7 owns mtiles [xcd*64, xcd*64+64); the 12 ntile-blocks of an
// mtile run on one XCD -> A panel fetched once into that XCD's L2.
__global__ __launch_bounds__(256, 4) void k_qkv(
    const f16* __restrict__ A, const f16* __restrict__ Bw,
    const float* __restrict__ bq, const float* __restrict__ bk,
    const float* __restrict__ bv,
    f16* __restrict__ qb, f16* __restrict__ kb, f16* __restrict__ vb) {
  __shared__ f16 la[3 * 4096];
  __shared__ f16 lb[3 * 4096];
  const int tid = threadIdx.x;
  const int w = tid >> 6, lane = tid & 63;
  const int ln = lane & 15, g = lane >> 4;
  const int wr = w >> 1, wc = w & 1;
  const int s = blockIdx.x >> 3;
  const int ml = s / 12;
  const int ntile = s - ml * 12;
  const int mtile = (blockIdx.x & 7) * 64 + ml;

  f32x4 acc[4][4] = {};
  gemm128_pf(A + mtile * 128 * KD, Bw + ntile * 128 * KD, la, lb, acc);

  const int b = mtile;  // 128 rows per tile == one batch
  const int colbase = ntile * 128 + wc * 64;
#pragma unroll
  for (int m = 0; m < 4; ++m) {
    const int nn0 = wr * 64 + m * 16 + g * 4;  // token row in batch (reg 0)
#pragma unroll
    for (int n = 0; n < 4; ++n) {
      const int col = colbase + n * 16 + ln;
      const int which = col >> 9;      // 0=Q 1=K 2=V (uniform per n)
      const int c = col & 511;
      const int h = c >> 6, d = c & 63;
      const float bias = (which == 0) ? bq[c] : (which == 1) ? bk[c] : bv[c];
      if (which < 2) {
        f16* dst = ((which == 0) ? qb : kb) + ((b * NH + h) * NQ + nn0) * DH + d;
#pragma unroll
        for (int r = 0; r < 4; ++r)
          dst[r * DH] = (f16)(acc[m][n][r] + bias);
      } else {
        half4 v4;
#pragma unroll
        for (int r = 0; r < 4; ++r)
          v4[r] = (f16)(acc[m][n][r] + bias);
        *(half4*)(vb + ((b * NH + h) * DH + d) * NQ + nn0) = v4;  // V^T
      }
    }
  }
}

// ---------------- kernel 2: causal attention, one block per (b,h) ----------------
__global__ __launch_bounds__(256, 2) void k_attn(
    const f16* __restrict__ qbuf, const f16* __restrict__ kbuf,
    const f16* __restrict__ vbuf, f16* __restrict__ ao) {
  __shared__ f16 kl[128 * 72];   // K [key][d], padded stride 72
  __shared__ f16 vl[64 * 136];   // V^T [d][key], padded stride 136
  __shared__ f16 pl[128 * 136];  // P [q][key], padded stride 136
  const int bh = blockIdx.x;
  const f16* Qp = qbuf + bh * (NQ * DH);
  const f16* Kp = kbuf + bh * (NQ * DH);
  const f16* Vp = vbuf + bh * (DH * NQ);
  const int tid = threadIdx.x;
  const int w = tid >> 6, lane = tid & 63;
  const int ln = lane & 15, g = lane >> 4;

#pragma unroll
  for (int i = 0; i < 4; ++i) {
    const int e = i * 2048 + tid * 8;
    *(half8*)(kl + (e >> 6) * 72 + (e & 63)) = *(const half8*)(Kp + e);
  }
#pragma unroll
  for (int i = 0; i < 4; ++i) {
    const int e = i * 2048 + tid * 8;
    *(half8*)(vl + (e >> 7) * 136 + (e & 127)) = *(const half8*)(Vp + e);
  }
  half8 qf[2][2];
#pragma unroll
  for (int m = 0; m < 2; ++m)
#pragma unroll
    for (int ks = 0; ks < 2; ++ks)
      qf[m][ks] = *(const half8*)(Qp + (w * 32 + m * 16 + ln) * DH + ks * 32 + g * 8);
  __syncthreads();

  f32x4 s[2][8] = {};
#pragma unroll
  for (int ks = 0; ks < 2; ++ks)
#pragma unroll
    for (int n = 0; n < 8; ++n) {
      half8 kf = *(const half8*)(kl + (n * 16 + ln) * 72 + ks * 32 + g * 8);
      s[0][n] = MFMA16(qf[0][ks], kf, s[0][n]);
      s[1][n] = MFMA16(qf[1][ks], kf, s[1][n]);
    }

  float inv[2][4];
#pragma unroll
  for (int m = 0; m < 2; ++m) {
#pragma unroll
    for (int r = 0; r < 4; ++r) {
      const int q = w * 32 + m * 16 + g * 4 + r;
      float z[8];
      float rm = -1e30f;
#pragma unroll
      for (int n = 0; n < 8; ++n) {
        const int col = n * 16 + ln;
        float zz = s[m][n][r] * 0.125f + ((col > q) ? -12500.0f : 0.0f);
        z[n] = zz;
        rm = fmaxf(rm, zz);
      }
      rm = fmaxf(rm, __shfl_xor(rm, 1));
      rm = fmaxf(rm, __shfl_xor(rm, 2));
      rm = fmaxf(rm, __shfl_xor(rm, 4));
      rm = fmaxf(rm, __shfl_xor(rm, 8));
      float rs = 0.f;
#pragma unroll
      for (int n = 0; n < 8; ++n) {
        const float p = __expf(z[n] - rm);   // masked cols -> exact 0
        rs += p;
        pl[q * 136 + n * 16 + ln] = (f16)p;  // unnormalized P
      }
      rs += __shfl_xor(rs, 1);
      rs += __shfl_xor(rs, 2);
      rs += __shfl_xor(rs, 4);
      rs += __shfl_xor(rs, 8);
      inv[m][r] = 1.0f / rs;
    }
  }

  f32x4 o[2][4] = {};
#pragma unroll
  for (int ks = 0; ks < 4; ++ks) {
    half8 pf0 = *(const half8*)(pl + (w * 32 + ln) * 136 + ks * 32 + g * 8);
    half8 pf1 = *(const half8*)(pl + (w * 32 + 16 + ln) * 136 + ks * 32 + g * 8);
#pragma unroll
    for (int n = 0; n < 4; ++n) {
      half8 vf = *(const half8*)(vl + (n * 16 + ln) * 136 + ks * 32 + g * 8);
      o[0][n] = MFMA16(pf0, vf, o[0][n]);
      o[1][n] = MFMA16(pf1, vf, o[1][n]);
    }
  }

  const int b = bh >> 3, h = bh & 7;
  f16* dst = ao + (b * NQ) * CH + h * DH;
#pragma unroll
  for (int m = 0; m < 2; ++m)
#pragma unroll
    for (int n = 0; n < 4; ++n)
#pragma unroll
      for (int r = 0; r < 4; ++r) {
        const int q = w * 32 + m * 16 + g * 4 + r;
        dst[q * CH + n * 16 + ln] = (f16)(o[m][n][r] * inv[m][r]);
      }
}

// ---------------- kernel 3: output projection GEMM (prefetched core) ----------------
__global__ __launch_bounds__(256, 4) void k_out(
    const f16* __restrict__ A, const f16* __restrict__ Bw,
    const float* __restrict__ bo, float* __restrict__ out) {
  __shared__ f16 la[3 * 4096];
  __shared__ f16 lb[3 * 4096];
  const int tid = threadIdx.x;
  const int w = tid >> 6, lane = tid & 63;
  const int ln = lane & 15, g = lane >> 4;
  const int wr = w >> 1, wc = w & 1;
  const int s = blockIdx.x >> 3;
  const int ml = s >> 2;
  const int ntile = s & 3;
  const int mtile = (blockIdx.x & 7) * 64 + ml;

  f32x4 acc[4][4] = {};
  gemm128_pf(A + mtile * 128 * KD, Bw + ntile * 128 * KD, la, lb, acc);

  const int colbase = ntile * 128 + wc * 64;
#pragma unroll
  for (int m = 0; m < 4; ++m) {
    const int tok0 = mtile * 128 + wr * 64 + m * 16 + g * 4;
#pragma unroll
    for (int n = 0; n < 4; ++n) {
      const int col = colbase + n * 16 + ln;
      const float bias = bo[col];
      float* dst = out + tok0 * CH + col;
#pragma unroll
      for (int r = 0; r < 4; ++r)
        dst[r * CH] = acc[m][n][r] + bias;
    }
  }
}

extern "C" void kernel_launch(void* const* d_in, const int* in_sizes, int n_in,
                              void* d_out, int out_size, void* d_ws, size_t ws_size,
                              hipStream_t stream) {
  (void)in_sizes; (void)n_in; (void)out_size; (void)ws_size;
  const float* x  = (const float*)d_in[0];
  const float* Wq = (const float*)d_in[1];
  const float* bq = (const float*)d_in[2];
  const float* Wk = (const float*)d_in[3];
  const float* bk = (const float*)d_in[4];
  const float* Wv = (const float*)d_in[5];
  const float* bv = (const float*)d_in[6];
  const float* Wo = (const float*)d_in[7];
  const float* bo = (const float*)d_in[8];
  float* out = (float*)d_out;

  char* ws = (char*)d_ws;
  const size_t SZ = (size_t)MTOK * KD * sizeof(f16);  // 64 MB
  f16* xb = (f16*)(ws);                // x in fp16
  f16* qb = (f16*)(ws + SZ);           // Q [b][h][n][d]
  f16* kb = (f16*)(ws + 2 * SZ);       // K [b][h][n][d]
  f16* vb = (f16*)(ws + 3 * SZ);       // V^T [b][h][d][n]
  f16* wt = (f16*)(ws + 4 * SZ);       // W^T fp16, 2048x512
  f16* ao = xb;                        // attn out aliases xb (xb dead by then)

  k_prep<<<2560, 256, 0, stream>>>(x, Wq, Wk, Wv, Wo, xb, wt);
  k_qkv<<<6144, 256, 0, stream>>>(xb, wt, bq, bk, bv, qb, kb, vb);
  k_attn<<<4096, 256, 0, stream>>>(qb, kb, vb, ao);
  k_out<<<2048, 256, 0, stream>>>(ao, wt + 1536 * KD, bo, out);
}

// Round 6
// 331.407 us; speedup vs baseline: 1.0068x; 1.0068x over previous
//
#include <hip/hip_runtime.h>

typedef _Float16 f16;
typedef _Float16 half8 __attribute__((ext_vector_type(8)));
typedef _Float16 half4 __attribute__((ext_vector_type(4)));
typedef float f32x4 __attribute__((ext_vector_type(4)));

#define B_SZ 512
#define NQ   128
#define CH   512
#define NH   8
#define DH   64
#define MTOK (B_SZ*NQ)   // 65536 tokens
#define KD   512

#define MFMA16(a,b,c) __builtin_amdgcn_mfma_f32_16x16x32_f16((a),(b),(c),0,0,0)

// global -> LDS direct DMA, 16B per lane. LDS dest is wave-uniform base + lane*16.
#define GLDS16(g,l) __builtin_amdgcn_global_load_lds( \
    (__attribute__((address_space(1))) void*)(g), \
    (__attribute__((address_space(3))) void*)(l), 16, 0, 0)

// ---------------- kernel 0: x fp32->fp16  +  W^T fp32->fp16, one launch ----------------
__global__ __launch_bounds__(256) void k_prep(
    const float* __restrict__ x,
    const float* __restrict__ Wq, const float* __restrict__ Wk,
    const float* __restrict__ Wv, const float* __restrict__ Wo,
    f16* __restrict__ xb, f16* __restrict__ wt) {
  const int bid = blockIdx.x;
  if (bid < 512) {
    for (int e = threadIdx.x; e < 2048; e += 256) {
      const int n = bid * 4 + (e >> 9);
      const int k = e & 511;
      const float* W = (n < 512) ? Wq : (n < 1024) ? Wk : (n < 1536) ? Wv : Wo;
      wt[n * 512 + k] = (f16)W[k * 512 + (n & 511)];
    }
  } else {
    const int n8 = MTOK * KD / 8;
    int i = (bid - 512) * 256 + threadIdx.x;
    const int stride = 2048 * 256;
    for (; i < n8; i += stride) {
      f32x4 a = ((const f32x4*)x)[2 * i];
      f32x4 b = ((const f32x4*)x)[2 * i + 1];
      half8 h;
      h[0] = (f16)a[0]; h[1] = (f16)a[1]; h[2] = (f16)a[2]; h[3] = (f16)a[3];
      h[4] = (f16)b[0]; h[5] = (f16)b[1]; h[6] = (f16)b[2]; h[7] = (f16)b[3];
      ((half8*)xb)[i] = h;
    }
  }
}

// ========== chained 128x128 GEMM core: NCH mtiles per block, T = NCH*16 K-steps ==========
// BK=32, depth-2 prefetch over 3 static LDS buffers (unroll-by-3 -> compile-time LDS
// addrs). T2 swizzle as R4 (pre-swizzled global source + swizzled ds_read). Counted
// vmcnt(4) gates throughout; staging runs seamlessly across mtile boundaries; the
// per-mtile epilogue executes after a barrier while the next mtile's tiles are in
// flight. B panel (one ntile) is re-staged per mtile from L2 (tiny, hot).
__device__ __forceinline__ void step128(const f16* pa, const f16* pb,
                                        int roA, int roB, f32x4 (&acc)[4][4]) {
  half8 af[4], bf[4];
#pragma unroll
  for (int m = 0; m < 4; ++m) af[m] = *(const half8*)(pa + roA + m * 512);
#pragma unroll
  for (int n = 0; n < 4; ++n) bf[n] = *(const half8*)(pb + roB + n * 512);
  __builtin_amdgcn_s_setprio(1);
#pragma unroll
  for (int m = 0; m < 4; ++m)
#pragma unroll
    for (int n = 0; n < 4; ++n)
      acc[m][n] = MFMA16(af[m], bf[n], acc[m][n]);
  __builtin_amdgcn_s_setprio(0);
}

template<int T, class Epi>
__device__ __forceinline__ void gemm_chain(
    const f16* __restrict__ gA,   // per-thread staging base (chain row 0, incl srow/scol)
    const f16* __restrict__ gB,   // per-thread staging base (B panel)
    f16* la, f16* lb, int w512, int roA, int roB, Epi epi) {
  const f32x4 z = {0.f, 0.f, 0.f, 0.f};
  f32x4 acc[4][4] = {};

#define STAGE(v, bufc) do { \
    const int aoff = (((v) >> 4) << 16) + (((v) & 15) << 5); \
    const int boff = ((v) & 15) << 5; \
    f16* lav = la + (bufc) * 4096 + w512; \
    f16* lbv = lb + (bufc) * 4096 + w512; \
    GLDS16(gA + aoff, lav); GLDS16(gA + aoff + 64 * KD, lav + 2048); \
    GLDS16(gB + boff, lbv); GLDS16(gB + boff + 64 * KD, lbv + 2048); \
  } while (0)

  STAGE(0, 0); STAGE(1, 1);
  asm volatile("s_waitcnt vmcnt(4)" ::: "memory");
  __builtin_amdgcn_s_barrier();

  constexpr int LASTU = 3 * ((T - 5) / 3);   // last main-loop u (stages v=u+i+2 <= T-1)
#pragma unroll 1
  for (int u = 0; u <= LASTU; u += 3) {
#pragma unroll
    for (int i = 0; i < 3; ++i) {
      STAGE(u + i + 2, (i + 2) % 3);                       // buf static
      step128(la + i * 4096, lb + i * 4096, roA, roB, acc); // buf static
      asm volatile("s_waitcnt vmcnt(4)" ::: "memory");      // step u+i+1 landed
      __builtin_amdgcn_s_barrier();
      if (((u + i) & 15) == 15) {    // uniform; end of an mtile (never the last one here)
        epi(acc, (u + i) >> 4);
#pragma unroll
        for (int m = 0; m < 4; ++m)
#pragma unroll
          for (int n = 0; n < 4; ++n) acc[m][n] = z;
      }
    }
  }
  constexpr int RS = LASTU + 3;   // RS % 3 == 0
#pragma unroll
  for (int r = 0; r < T - RS; ++r) {
    const int s = RS + r;          // static under unroll
    if (s + 2 < T) STAGE(s + 2, (s + 2) % 3);
    step128(la + (s % 3) * 4096, lb + (s % 3) * 4096, roA, roB, acc);
    if (s + 2 < T)      { asm volatile("s_waitcnt vmcnt(4)" ::: "memory"); }
    else if (s + 1 < T) { asm volatile("s_waitcnt vmcnt(0)" ::: "memory"); }
    if (s + 1 < T) __builtin_amdgcn_s_barrier();
  }
  epi(acc, (T - 1) >> 4);
#undef STAGE
}

// ---------------- kernel 1: fused QKV projection GEMM, chained (NCH=2) ----------------
__global__ __launch_bounds__(256, 3) void k_qkv(
    const f16* __restrict__ A, const f16* __restrict__ Bw,
    const float* __restrict__ bq, const float* __restrict__ bk,
    const float* __restrict__ bv,
    f16* __restrict__ qb, f16* __restrict__ kb, f16* __restrict__ vb) {
  __shared__ f16 la[3 * 4096];
  __shared__ f16 lb[3 * 4096];
  const int tid = threadIdx.x;
  const int w = tid >> 6, lane = tid & 63;
  const int ln = lane & 15, g = lane >> 4;
  const int wr = w >> 1, wc = w & 1;
  const int xcd = blockIdx.x & 7;
  const int s0 = blockIdx.x >> 3;            // 0..383
  const int cl = s0 / 12;                    // 0..31
  const int ntile = s0 - cl * 12;            // 0..11
  const int chain = xcd * 32 + cl;           // 0..255 ; mtiles chain*2, chain*2+1

  const int srow = w * 16 + (lane >> 2);
  const int scol = ((lane & 3) ^ ((lane >> 3) & 3)) * 8;   // pre-swizzled source slot
  const f16* gA = A + (size_t)chain * 2 * 128 * KD + srow * KD + scol;
  const f16* gB = Bw + ntile * 128 * KD + srow * KD + scol;
  const int slotx = (g ^ ((ln >> 1) & 3)) * 8;             // swizzled read slot
  const int roA = (wr * 64 + ln) * 32 + slotx;
  const int roB = (wc * 64 + ln) * 32 + slotx;

  const int colbase = ntile * 128 + wc * 64;
  auto epi = [&](f32x4 (&acc)[4][4], int j) {
    const int b = chain * 2 + j;   // mtile == batch
#pragma unroll
    for (int m = 0; m < 4; ++m) {
      const int nn0 = wr * 64 + m * 16 + g * 4;
#pragma unroll
      for (int n = 0; n < 4; ++n) {
        const int col = colbase + n * 16 + ln;
        const int which = col >> 9;      // 0=Q 1=K 2=V
        const int c = col & 511;
        const int h = c >> 6, d = c & 63;
        const float bias = (which == 0) ? bq[c] : (which == 1) ? bk[c] : bv[c];
        if (which < 2) {
          f16* dst = ((which == 0) ? qb : kb) + ((b * NH + h) * NQ + nn0) * DH + d;
#pragma unroll
          for (int r = 0; r < 4; ++r)
            dst[r * DH] = (f16)(acc[m][n][r] + bias);
        } else {
          half4 v4;
#pragma unroll
          for (int r = 0; r < 4; ++r)
            v4[r] = (f16)(acc[m][n][r] + bias);
          *(half4*)(vb + ((b * NH + h) * DH + d) * NQ + nn0) = v4;  // V^T
        }
      }
    }
  };
  gemm_chain<32>(gA, gB, la, lb, w * 512, roA, roB, epi);
}

// ---------------- kernel 2: causal attention, one block per (b,h) ----------------
__global__ __launch_bounds__(256, 2) void k_attn(
    const f16* __restrict__ qbuf, const f16* __restrict__ kbuf,
    const f16* __restrict__ vbuf, f16* __restrict__ ao) {
  __shared__ f16 kl[128 * 72];   // K [key][d], padded stride 72
  __shared__ f16 vl[64 * 136];   // V^T [d][key], padded stride 136
  __shared__ f16 pl[128 * 136];  // P [q][key], padded stride 136
  const int bh = blockIdx.x;
  const f16* Qp = qbuf + bh * (NQ * DH);
  const f16* Kp = kbuf + bh * (NQ * DH);
  const f16* Vp = vbuf + bh * (DH * NQ);
  const int tid = threadIdx.x;
  const int w = tid >> 6, lane = tid & 63;
  const int ln = lane & 15, g = lane >> 4;

#pragma unroll
  for (int i = 0; i < 4; ++i) {
    const int e = i * 2048 + tid * 8;
    *(half8*)(kl + (e >> 6) * 72 + (e & 63)) = *(const half8*)(Kp + e);
  }
#pragma unroll
  for (int i = 0; i < 4; ++i) {
    const int e = i * 2048 + tid * 8;
    *(half8*)(vl + (e >> 7) * 136 + (e & 127)) = *(const half8*)(Vp + e);
  }
  half8 qf[2][2];
#pragma unroll
  for (int m = 0; m < 2; ++m)
#pragma unroll
    for (int ks = 0; ks < 2; ++ks)
      qf[m][ks] = *(const half8*)(Qp + (w * 32 + m * 16 + ln) * DH + ks * 32 + g * 8);
  __syncthreads();

  f32x4 s[2][8] = {};
#pragma unroll
  for (int ks = 0; ks < 2; ++ks)
#pragma unroll
    for (int n = 0; n < 8; ++n) {
      half8 kf = *(const half8*)(kl + (n * 16 + ln) * 72 + ks * 32 + g * 8);
      s[0][n] = MFMA16(qf[0][ks], kf, s[0][n]);
      s[1][n] = MFMA16(qf[1][ks], kf, s[1][n]);
    }

  float inv[2][4];
#pragma unroll
  for (int m = 0; m < 2; ++m) {
#pragma unroll
    for (int r = 0; r < 4; ++r) {
      const int q = w * 32 + m * 16 + g * 4 + r;
      float z[8];
      float rm = -1e30f;
#pragma unroll
      for (int n = 0; n < 8; ++n) {
        const int col = n * 16 + ln;
        float zz = s[m][n][r] * 0.125f + ((col > q) ? -12500.0f : 0.0f);
        z[n] = zz;
        rm = fmaxf(rm, zz);
      }
      rm = fmaxf(rm, __shfl_xor(rm, 1));
      rm = fmaxf(rm, __shfl_xor(rm, 2));
      rm = fmaxf(rm, __shfl_xor(rm, 4));
      rm = fmaxf(rm, __shfl_xor(rm, 8));
      float rs = 0.f;
#pragma unroll
      for (int n = 0; n < 8; ++n) {
        const float p = __expf(z[n] - rm);   // masked cols -> exact 0
        rs += p;
        pl[q * 136 + n * 16 + ln] = (f16)p;  // unnormalized P
      }
      rs += __shfl_xor(rs, 1);
      rs += __shfl_xor(rs, 2);
      rs += __shfl_xor(rs, 4);
      rs += __shfl_xor(rs, 8);
      inv[m][r] = 1.0f / rs;
    }
  }

  f32x4 o[2][4] = {};
#pragma unroll
  for (int ks = 0; ks < 4; ++ks) {
    half8 pf0 = *(const half8*)(pl + (w * 32 + ln) * 136 + ks * 32 + g * 8);
    half8 pf1 = *(const half8*)(pl + (w * 32 + 16 + ln) * 136 + ks * 32 + g * 8);
#pragma unroll
    for (int n = 0; n < 4; ++n) {
      half8 vf = *(const half8*)(vl + (n * 16 + ln) * 136 + ks * 32 + g * 8);
      o[0][n] = MFMA16(pf0, vf, o[0][n]);
      o[1][n] = MFMA16(pf1, vf, o[1][n]);
    }
  }

  const int b = bh >> 3, h = bh & 7;
  f16* dst = ao + (b * NQ) * CH + h * DH;
#pragma unroll
  for (int m = 0; m < 2; ++m)
#pragma unroll
    for (int n = 0; n < 4; ++n)
#pragma unroll
      for (int r = 0; r < 4; ++r) {
        const int q = w * 32 + m * 16 + g * 4 + r;
        dst[q * CH + n * 16 + ln] = (f16)(o[m][n][r] * inv[m][r]);
      }
}

// ---------------- kernel 3: output projection GEMM, chained (NCH=2) ----------------
__global__ __launch_bounds__(256, 3) void k_out(
    const f16* __restrict__ A, const f16* __restrict__ Bw,
    const float* __restrict__ bo, float* __restrict__ out) {
  __shared__ f16 la[3 * 4096];
  __shared__ f16 lb[3 * 4096];
  const int tid = threadIdx.x;
  const int w = tid >> 6, lane = tid & 63;
  const int ln = lane & 15, g = lane >> 4;
  const int wr = w >> 1, wc = w & 1;
  const int xcd = blockIdx.x & 7;
  const int s0 = blockIdx.x >> 3;            // 0..127
  const int ntile = s0 & 3;
  const int chain = xcd * 32 + (s0 >> 2);    // 0..255

  const int srow = w * 16 + (lane >> 2);
  const int scol = ((lane & 3) ^ ((lane >> 3) & 3)) * 8;
  const f16* gA = A + (size_t)chain * 2 * 128 * KD + srow * KD + scol;
  const f16* gB = Bw + ntile * 128 * KD + srow * KD + scol;
  const int slotx = (g ^ ((ln >> 1) & 3)) * 8;
  const int roA = (wr * 64 + ln) * 32 + slotx;
  const int roB = (wc * 64 + ln) * 32 + slotx;

  const int colbase = ntile * 128 + wc * 64;
  auto epi = [&](f32x4 (&acc)[4][4], int j) {
    const int mtile = chain * 2 + j;
#pragma unroll
    for (int m = 0; m < 4; ++m) {
      const int tok0 = mtile * 128 + wr * 64 + m * 16 + g * 4;
#pragma unroll
      for (int n = 0; n < 4; ++n) {
        const int col = colbase + n * 16 + ln;
        const float bias = bo[col];
        float* dst = out + (size_t)tok0 * CH + col;
#pragma unroll
        for (int r = 0; r < 4; ++r)
          dst[r * CH] = acc[m][n][r] + bias;
      }
    }
  };
  gemm_chain<32>(gA, gB, la, lb, w * 512, roA, roB, epi);
}

extern "C" void kernel_launch(void* const* d_in, const int* in_sizes, int n_in,
                              void* d_out, int out_size, void* d_ws, size_t ws_size,
                              hipStream_t stream) {
  (void)in_sizes; (void)n_in; (void)out_size; (void)ws_size;
  const float* x  = (const float*)d_in[0];
  const float* Wq = (const float*)d_in[1];
  const float* bq = (const float*)d_in[2];
  const float* Wk = (const float*)d_in[3];
  const float* bk = (const float*)d_in[4];
  const float* Wv = (const float*)d_in[5];
  const float* bv = (const float*)d_in[6];
  const float* Wo = (const float*)d_in[7];
  const float* bo = (const float*)d_in[8];
  float* out = (float*)d_out;

  char* ws = (char*)d_ws;
  const size_t SZ = (size_t)MTOK * KD * sizeof(f16);  // 64 MB
  f16* xb = (f16*)(ws);                // x in fp16
  f16* qb = (f16*)(ws + SZ);           // Q [b][h][n][d]
  f16* kb = (f16*)(ws + 2 * SZ);       // K [b][h][n][d]
  f16* vb = (f16*)(ws + 3 * SZ);       // V^T [b][h][d][n]
  f16* wt = (f16*)(ws + 4 * SZ);       // W^T fp16, 2048x512
  f16* ao = xb;                        // attn out aliases xb (xb dead by then)

  k_prep<<<2560, 256, 0, stream>>>(x, Wq, Wk, Wv, Wo, xb, wt);
  k_qkv<<<3072, 256, 0, stream>>>(xb, wt, bq, bk, bv, qb, kb, vb);
  k_attn<<<4096, 256, 0, stream>>>(qb, kb, vb, ao);
  k_out<<<1024, 256, 0, stream>>>(ao, wt + 1536 * KD, bo, out);
}